// Round 8
// baseline (150.498 us; speedup 1.0000x reference)
//
#include <hip/hip_runtime.h>
#include <stdint.h>

// FSUMGUCell: hy = (1-fg)*ng + fg*hx
//   fg = ( [hx|x]@w_f^T + b_f + 1 ) * 0.5
//   ng =   [fg*hx|x]@w_n^T + b_n
// B=H=I=2048, K=H+I=4096. bf16 MFMA path.
//
// Round 8: BARRIER-FREE K-loop. Each wave owns private LDS strips
// [wave][2buf][A|B][64x32] (16KB/wave, 128KB block) and stages its own
// A/B 64-row strips (BK=32). vmcnt is per-wave, LDS strips are per-wave ->
// no s_barrier until the final split-K reduce. SIMD scheduler free-runs
// 8 decoupled wave-pipelines (r4/r6 showed the shared barrier was the
// serializer; 46% busy, 3x MFMA floor). Cost: A/B staged 2x (FETCH ~2x).

#define Hdim 2048
#define Idim 2048
#define Bdim 2048
#define Ktot 4096
#define KHALF 2048
#define BK 32
#define NSTEP (KHALF / BK)   // 64

typedef __bf16 bf16;
typedef __bf16 bf16x8 __attribute__((ext_vector_type(8)));
typedef float  f32x4  __attribute__((ext_vector_type(4)));

__device__ __forceinline__ void gload_lds16(const bf16* g, bf16* l) {
  __builtin_amdgcn_global_load_lds(
      (const __attribute__((address_space(1))) unsigned int*)g,
      (__attribute__((address_space(3))) unsigned int*)l,
      16, 0, 0);
}

// ---- fused prep: Wf cvt | Wn cvt | A1 = [hx|x] cvt (all f32 -> bf16 x8) ----
__global__ void prep_kernel(const float* __restrict__ w_f, const float* __restrict__ w_n,
                            const float* __restrict__ hx, const float* __restrict__ x,
                            bf16* __restrict__ Wf, bf16* __restrict__ Wn,
                            bf16* __restrict__ A1) {
  const int n8 = Hdim * Ktot / 8;
  int stride = gridDim.x * blockDim.x;
  for (int i = blockIdx.x * blockDim.x + threadIdx.x; i < 3 * n8; i += stride) {
    const float* src;
    bf16* dst;
    if (i < n8) {
      src = w_f + (size_t)i * 8;  dst = Wf + (size_t)i * 8;
    } else if (i < 2 * n8) {
      int j = i - n8;
      src = w_n + (size_t)j * 8;  dst = Wn + (size_t)j * 8;
    } else {
      int j = i - 2 * n8;
      int e = j * 8;
      int b = e >> 12;
      int k = e & (Ktot - 1);
      src = (k < Hdim) ? (hx + (size_t)b * Hdim + k)
                       : (x  + (size_t)b * Idim + (k - Hdim));
      dst = A1 + (size_t)e;
    }
    const float4* s = (const float4*)src;
    float4 va = s[0], vb = s[1];
    bf16x8 o;
    o[0]=(bf16)va.x; o[1]=(bf16)va.y; o[2]=(bf16)va.z; o[3]=(bf16)va.w;
    o[4]=(bf16)vb.x; o[5]=(bf16)vb.y; o[6]=(bf16)vb.z; o[7]=(bf16)vb.w;
    *((bf16x8*)dst) = o;
  }
}

// ---- 128x128 GEMM, split-K x2, 8 waves, barrier-free private pipelines ----
// C[row][col] = sum_k Asrc[row][k] * W[col][k], W [2048][4096] bf16 (B^T).
// Wave (g,sub): g = K-half, sub = 64x64 output quadrant. Per step each wave
// stages its own A strip (64 rows x 32 k) + B strip into private LDS.
// Strip swizzle (4 chunks of 16B per 64B row): logical chunk q of row r is
// stored at chunk q ^ ((r>>1)&3); staged via inverse-swizzled global source
// (global_load_lds writes linearly); read applies the same XOR.
template<int EPI>
__global__ __launch_bounds__(512)
void gemm_kernel(const bf16* __restrict__ A1, const bf16* __restrict__ A2L,
                 const bf16* __restrict__ W,
                 const float* __restrict__ bias,
                 const float* __restrict__ hx,   // EPI0 only
                 bf16* __restrict__ OMF,         // EPI0: write (1-fg) ; EPI1: read
                 bf16* __restrict__ A2Lw,        // EPI0: write bf16(fg*hx)
                 float* __restrict__ OUT)        // EPI1: write hy
{
  __shared__ bf16 lds[8][2][2][64 * BK];   // [wave][buf][A=0/B=1][2048] = 128 KB

  int bid  = blockIdx.x;
  int sbid = (bid & 7) * 32 + (bid >> 3);   // XCD swizzle (256%8==0, bijective)
  int tm = sbid >> 4, tn = sbid & 15;

  int tid  = threadIdx.x;
  int w = tid >> 6, lane = tid & 63;
  int g = w >> 2, sub = w & 3;
  int wrow = (sub >> 1) * 64;   // 64x64 quadrant per wave
  int wcol = (sub & 1) * 64;
  int fr = lane & 15, fq = lane >> 4;
  int permr = (fr >> 1) & 3;    // read-side chunk XOR

  // staging: per gload i (i=0..3 per operand), lane l writes LDS elem
  // i*512 + l*8 -> strip row i*16 + (l>>2), dest chunk l&3. Source logical
  // chunk = (l&3) ^ ((l>>3)&3) (inverse swizzle; (i*8)&3 == 0).
  int srowL   = lane >> 2;                        // 0..15
  int schunkL = (lane & 3) ^ ((lane >> 3) & 3);

  const bf16* pAl;
  size_t strA;
  if (EPI == 0) {
    pAl = A1 + (size_t)(tm * 128 + wrow + srowL) * Ktot + schunkL * 8 + g * KHALF;
    strA = Ktot;
  } else if (g == 0) {
    pAl = A2L + (size_t)(tm * 128 + wrow + srowL) * KHALF + schunkL * 8;  // fg*hx
    strA = KHALF;
  } else {
    pAl = A1 + (size_t)(tm * 128 + wrow + srowL) * Ktot + schunkL * 8 + Hdim; // x
    strA = Ktot;
  }
  const bf16* pBl = W + (size_t)(tn * 128 + wcol + srowL) * Ktot + schunkL * 8 + g * KHALF;

#define STAGE(buf_, t_) do {                                                   \
    _Pragma("unroll")                                                          \
    for (int i = 0; i < 4; ++i) {                                              \
      gload_lds16(pAl + (size_t)i * 16 * strA + (t_) * BK, &lds[w][buf_][0][i * 512]); \
      gload_lds16(pBl + (size_t)i * 16 * Ktot + (t_) * BK, &lds[w][buf_][1][i * 512]); \
    }                                                                          \
  } while (0)

  f32x4 acc[4][4] = {};

  STAGE(0, 0);
  int cur = 0;
  for (int t = 0; t < NSTEP; ++t) {
    if (t + 1 < NSTEP) {
      STAGE(cur ^ 1, t + 1);                            // 8 new loads in flight
      asm volatile("s_waitcnt vmcnt(8)" ::: "memory");  // wait only step-t's 8
    } else {
      asm volatile("s_waitcnt vmcnt(0)" ::: "memory");
    }
    bf16x8 af[4], bv[4];
    int ch = (fq ^ permr) * 8;
    #pragma unroll
    for (int m = 0; m < 4; ++m)
      af[m] = *(const bf16x8*)&lds[w][cur][0][(m * 16 + fr) * BK + ch];
    #pragma unroll
    for (int n = 0; n < 4; ++n)
      bv[n] = *(const bf16x8*)&lds[w][cur][1][(n * 16 + fr) * BK + ch];
    __builtin_amdgcn_s_setprio(1);
    #pragma unroll
    for (int m = 0; m < 4; ++m)
      #pragma unroll
      for (int n = 0; n < 4; ++n)
        acc[m][n] = __builtin_amdgcn_mfma_f32_16x16x32_bf16(af[m], bv[n], acc[m][n], 0, 0, 0);
    __builtin_amdgcn_s_setprio(0);
    cur ^= 1;
  }
#undef STAGE

  // ---- cross-group reduction via LDS (reuse strip space), fused epilogue ----
  __syncthreads();
  float* xch = (float*)&lds[0][0][0][0];    // 4 subs x 16 KB = 64 KB
  if (g == 1) {
    #pragma unroll
    for (int m = 0; m < 4; ++m)
      #pragma unroll
      for (int n = 0; n < 4; ++n)
        *(f32x4*)&xch[sub * 4096 + (m * 4 + n) * 256 + lane * 4] = acc[m][n];
  }
  __syncthreads();
  if (g == 0) {
    // C/D layout: col = lane&15, row = (lane>>4)*4 + i  [m89 verified]
    int row0 = tm * 128 + wrow + fq * 4;
    int col0 = tn * 128 + wcol + fr;
    #pragma unroll
    for (int n = 0; n < 4; ++n) {
      int gcol = col0 + n * 16;
      float bv2 = bias[gcol];
      #pragma unroll
      for (int m = 0; m < 4; ++m) {
        f32x4 part = *(const f32x4*)&xch[sub * 4096 + (m * 4 + n) * 256 + lane * 4];
        #pragma unroll
        for (int i = 0; i < 4; ++i) {
          int grow = row0 + m * 16 + i;
          size_t idx = (size_t)grow * Hdim + gcol;
          float v = acc[m][n][i] + part[i] + bv2;
          if (EPI == 0) {
            float fg   = (v + 1.0f) * 0.5f;
            float fghx = fg * hx[idx];
            OMF[idx]  = (bf16)(1.0f - fg);                  // (1-fg) bf16
            A2Lw[(size_t)grow * KHALF + gcol] = (bf16)fghx; // GEMM2 A left half
          } else {
            float omf  = (float)OMF[idx];                   // 1-fg (bf16)
            float fghx = (float)A2L[idx];                   // bf16(fg*hx)
            OUT[idx] = omf * v + fghx;                      // (1-fg)*ng + fg*hx
          }
        }
      }
    }
  }
}

extern "C" void kernel_launch(void* const* d_in, const int* in_sizes, int n_in,
                              void* d_out, int out_size, void* d_ws, size_t ws_size,
                              hipStream_t stream) {
  const float* x   = (const float*)d_in[0];
  const float* hx  = (const float*)d_in[1];
  const float* w_f = (const float*)d_in[2];
  const float* b_f = (const float*)d_in[3];
  const float* w_n = (const float*)d_in[4];
  const float* b_n = (const float*)d_in[5];
  float* out = (float*)d_out;

  bf16* A1  = (bf16*)d_ws;                       // [2048][4096] = 16 MB
  bf16* A2L = A1  + (size_t)Bdim * Ktot;         // [2048][2048] =  8 MB
  bf16* Wf  = A2L + (size_t)Bdim * KHALF;        // [2048][4096] = 16 MB
  bf16* Wn  = Wf  + (size_t)Hdim * Ktot;         // [2048][4096] = 16 MB
  bf16* OMF = Wn  + (size_t)Hdim * Ktot;         // [2048][2048] =  8 MB
  // total 64 MB

  prep_kernel<<<2048, 256, 0, stream>>>(w_f, w_n, hx, x, Wf, Wn, A1);

  // GEMM1: fg path -> omf (1-fg, bf16) + A2L (bf16 fg*hx).
  gemm_kernel<0><<<256, 512, 0, stream>>>(A1, nullptr, Wf, b_f, hx, OMF, A2L, nullptr);
  // GEMM2: ng path; A = [A2L | A1 right half]; hy -> d_out.
  gemm_kernel<1><<<256, 512, 0, stream>>>(A1, A2L, Wn, b_n, nullptr, OMF, nullptr, out);
}

// Round 9
// 123.838 us; speedup vs baseline: 1.2153x; 1.2153x over previous
//
#include <hip/hip_runtime.h>
#include <stdint.h>

// FSUMGUCell: hy = (1-fg)*ng + fg*hx
//   fg = ( [hx|x]@w_f^T + b_f + 1 ) * 0.5
//   ng =   [fg*hx|x]@w_n^T + b_n
// B=H=I=2048, K=H+I=4096. bf16 MFMA path.
//
// Round 9: split-K ACROSS BLOCKS. grid 512 = 256 output tiles x 2 K-halves;
// each block = 4 waves, 128x128 tile, K=2048, BK=64 dbuf LDS (64 KB) with
// counted vmcnt(8) — the verified r3 group pipeline, one group per block.
// 64 KB LDS -> 2 blocks/CU co-resident: one block's barrier/vmcnt stalls are
// filled by the other block's MFMA (m102: same structure 2.6x faster at
// >=3 blocks/CU vs 1). Nonlinear epilogues move to elementwise combine
// kernels. Partials: P0 = d_out, P1 = ws (+16 MB; ws total 80 MB).

#define Hdim 2048
#define Idim 2048
#define Bdim 2048
#define Ktot 4096
#define KHALF 2048
#define NSTEP (KHALF / 64)   // 32

typedef __bf16 bf16;
typedef __bf16 bf16x8 __attribute__((ext_vector_type(8)));
typedef float  f32x4  __attribute__((ext_vector_type(4)));

__device__ __forceinline__ void gload_lds16(const bf16* g, bf16* l) {
  __builtin_amdgcn_global_load_lds(
      (const __attribute__((address_space(1))) unsigned int*)g,
      (__attribute__((address_space(3))) unsigned int*)l,
      16, 0, 0);
}

// ---- fused prep: Wf cvt | Wn cvt | A1 = [hx|x] cvt (all f32 -> bf16 x8) ----
__global__ void prep_kernel(const float* __restrict__ w_f, const float* __restrict__ w_n,
                            const float* __restrict__ hx, const float* __restrict__ x,
                            bf16* __restrict__ Wf, bf16* __restrict__ Wn,
                            bf16* __restrict__ A1) {
  const int n8 = Hdim * Ktot / 8;
  int stride = gridDim.x * blockDim.x;
  for (int i = blockIdx.x * blockDim.x + threadIdx.x; i < 3 * n8; i += stride) {
    const float* src;
    bf16* dst;
    if (i < n8) {
      src = w_f + (size_t)i * 8;  dst = Wf + (size_t)i * 8;
    } else if (i < 2 * n8) {
      int j = i - n8;
      src = w_n + (size_t)j * 8;  dst = Wn + (size_t)j * 8;
    } else {
      int j = i - 2 * n8;
      int e = j * 8;
      int b = e >> 12;
      int k = e & (Ktot - 1);
      src = (k < Hdim) ? (hx + (size_t)b * Hdim + k)
                       : (x  + (size_t)b * Idim + (k - Hdim));
      dst = A1 + (size_t)e;
    }
    const float4* s = (const float4*)src;
    float4 va = s[0], vb = s[1];
    bf16x8 o;
    o[0]=(bf16)va.x; o[1]=(bf16)va.y; o[2]=(bf16)va.z; o[3]=(bf16)va.w;
    o[4]=(bf16)vb.x; o[5]=(bf16)vb.y; o[6]=(bf16)vb.z; o[7]=(bf16)vb.w;
    *((bf16x8*)dst) = o;
  }
}

// ---- 128x128 x K=2048 partial GEMM, 4 waves, dbuf + counted vmcnt ----
// grid 512: bid = tile*2 + kpart. P[kpart][row][col] = sum_k A[row][k]*W[col][k]
// (no bias; added in combine). A source per kpart: base Ab{0,1}, row stride
// sA{0,1} (lets GEMM2 read A2L for K-half 0 and A1-right (x) for K-half 1).
// LDS [2 buf][A|B][128*64] bf16 = 64 KB; 16B-chunk XOR swizzle: LDS[row][c]
// holds global chunk c ^ (row&7), staged via inverse-swizzled global source
// (global_load_lds writes linearly); read applies the same XOR.
__global__ __launch_bounds__(256, 2)
void gemm_kernel(const bf16* __restrict__ Ab0, int sA0,
                 const bf16* __restrict__ Ab1, int sA1,
                 const bf16* __restrict__ W,
                 float* __restrict__ P0, float* __restrict__ P1)
{
  __shared__ bf16 lds[2][2][8192];   // [buf][A=0/B=1][128*64] = 64 KB

  int bid   = blockIdx.x;
  int tile  = bid >> 1;
  int kpart = bid & 1;
  int sbid = (tile & 7) * 32 + (tile >> 3);  // XCD swizzle on tile (256%8==0)
  int tm = sbid >> 4, tn = sbid & 15;

  int tid  = threadIdx.x;
  int sub = tid >> 6, lane = tid & 63;
  int wrow = (sub >> 1) * 64;   // 2x2 wave grid: 64x64 per wave
  int wcol = (sub & 1) * 64;
  int fr = lane & 15, fq = lane >> 4;
  int swz = fr & 7;

  // staging: 2048 16B chunks/step (A 1024 + B 1024), 256 thr -> 8 loads/thr.
  // Thread t, pass jj: row = jj*32 + (t>>3), dest chunk t&7, source chunk
  // (t&7)^(row&7) (inverse swizzle).
  int srow = tid >> 3;
  int csrc = (tid & 7) ^ (srow & 7);

  const bf16* pA = (kpart == 0)
      ? Ab0 + (size_t)(tm * 128 + srow) * sA0 + csrc * 8
      : Ab1 + (size_t)(tm * 128 + srow) * sA1 + csrc * 8;
  const size_t strA = (kpart == 0) ? (size_t)sA0 : (size_t)sA1;
  const bf16* pB = W + (size_t)(tn * 128 + srow) * Ktot + csrc * 8 + kpart * KHALF;
  int lbase = sub * 512;                     // + jj*2048 ; gload adds lane*16B

#define STAGE(buf, koff) do {                                                  \
    _Pragma("unroll")                                                          \
    for (int jj = 0; jj < 4; ++jj) {                                           \
      gload_lds16(pA + (size_t)jj * 32 * strA + (koff), &lds[buf][0][jj * 2048 + lbase]); \
      gload_lds16(pB + (size_t)jj * 32 * Ktot + (koff), &lds[buf][1][jj * 2048 + lbase]); \
    }                                                                          \
  } while (0)

  f32x4 acc[4][4] = {};

  auto compute = [&](int buf) {
    #pragma unroll
    for (int kk = 0; kk < 2; ++kk) {
      bf16x8 af[4], bv[4];
      int ch = ((kk * 4 + fq) ^ swz) * 8;
      #pragma unroll
      for (int m = 0; m < 4; ++m)
        af[m] = *(const bf16x8*)&lds[buf][0][(wrow + m * 16 + fr) * 64 + ch];
      #pragma unroll
      for (int n = 0; n < 4; ++n)
        bv[n] = *(const bf16x8*)&lds[buf][1][(wcol + n * 16 + fr) * 64 + ch];
      __builtin_amdgcn_s_setprio(1);
      #pragma unroll
      for (int m = 0; m < 4; ++m)
        #pragma unroll
        for (int n = 0; n < 4; ++n)
          acc[m][n] = __builtin_amdgcn_mfma_f32_16x16x32_bf16(af[m], bv[n], acc[m][n], 0, 0, 0);
      __builtin_amdgcn_s_setprio(0);
    }
  };

  STAGE(0, 0);
  int cur = 0;
  for (int t = 0; t < NSTEP - 1; ++t) {
    STAGE(cur ^ 1, (t + 1) * 64);                      // prefetch next K-tile
    asm volatile("s_waitcnt vmcnt(8)" ::: "memory");   // cur's 8 done; next 8 fly
    __builtin_amdgcn_s_barrier();
    compute(cur);
    __builtin_amdgcn_s_barrier();                      // reads done -> buf reusable
    cur ^= 1;
  }
  asm volatile("s_waitcnt vmcnt(0)" ::: "memory");
  __builtin_amdgcn_s_barrier();
  compute(cur);
#undef STAGE

  // partial write. C/D layout: col = lane&15, row = (lane>>4)*4 + i  [m89]
  float* Pd = kpart ? P1 : P0;
  int row0 = tm * 128 + wrow + fq * 4;
  int col0 = tn * 128 + wcol + fr;
  #pragma unroll
  for (int n = 0; n < 4; ++n) {
    int gcol = col0 + n * 16;
    #pragma unroll
    for (int m = 0; m < 4; ++m)
      #pragma unroll
      for (int i = 0; i < 4; ++i)
        Pd[(size_t)(row0 + m * 16 + i) * Hdim + gcol] = acc[m][n][i];
  }
}

// ---- combine1: c = P0+P1+b_f; fg=(c+1)/2; OMF=bf16(1-fg); A2L=bf16(fg*hx) ----
__global__ void combine1_kernel(const float* __restrict__ P0, const float* __restrict__ P1,
                                const float* __restrict__ bias, const float* __restrict__ hx,
                                bf16* __restrict__ OMF, bf16* __restrict__ A2L) {
  const int n4 = Bdim * Hdim / 4;
  int stride = gridDim.x * blockDim.x;
  for (int i = blockIdx.x * blockDim.x + threadIdx.x; i < n4; i += stride) {
    int col = (i * 4) & (Hdim - 1);
    float4 p0 = ((const float4*)P0)[i];
    float4 p1 = ((const float4*)P1)[i];
    float4 b  = *(const float4*)(bias + col);
    float4 h  = ((const float4*)hx)[i];
    bf16 omf[4], fghx[4];
    float c[4] = {p0.x+p1.x+b.x, p0.y+p1.y+b.y, p0.z+p1.z+b.z, p0.w+p1.w+b.w};
    float hv[4] = {h.x, h.y, h.z, h.w};
    #pragma unroll
    for (int j = 0; j < 4; ++j) {
      float fg = (c[j] + 1.0f) * 0.5f;
      omf[j]  = (bf16)(1.0f - fg);
      fghx[j] = (bf16)(fg * hv[j]);
    }
    *(ushort4*)(OMF + (size_t)i * 4) = *(ushort4*)omf;
    *(ushort4*)(A2L + (size_t)i * 4) = *(ushort4*)fghx;
  }
}

// ---- combine2: ng = P0+P1+b_n; hy = omf*ng + fghx -> OUT (over P0/d_out) ----
__global__ void combine2_kernel(const float* __restrict__ P0, const float* __restrict__ P1,
                                const float* __restrict__ bias,
                                const bf16* __restrict__ OMF, const bf16* __restrict__ A2L,
                                float* __restrict__ OUT) {
  const int n4 = Bdim * Hdim / 4;
  int stride = gridDim.x * blockDim.x;
  for (int i = blockIdx.x * blockDim.x + threadIdx.x; i < n4; i += stride) {
    int col = (i * 4) & (Hdim - 1);
    float4 p0 = ((const float4*)P0)[i];
    float4 p1 = ((const float4*)P1)[i];
    float4 b  = *(const float4*)(bias + col);
    ushort4 ou = *(const ushort4*)(OMF + (size_t)i * 4);
    ushort4 fu = *(const ushort4*)(A2L + (size_t)i * 4);
    const bf16* om = (const bf16*)&ou;
    const bf16* fh = (const bf16*)&fu;
    float c[4] = {p0.x+p1.x+b.x, p0.y+p1.y+b.y, p0.z+p1.z+b.z, p0.w+p1.w+b.w};
    float4 o;
    o.x = (float)om[0] * c[0] + (float)fh[0];
    o.y = (float)om[1] * c[1] + (float)fh[1];
    o.z = (float)om[2] * c[2] + (float)fh[2];
    o.w = (float)om[3] * c[3] + (float)fh[3];
    ((float4*)OUT)[i] = o;
  }
}

extern "C" void kernel_launch(void* const* d_in, const int* in_sizes, int n_in,
                              void* d_out, int out_size, void* d_ws, size_t ws_size,
                              hipStream_t stream) {
  const float* x   = (const float*)d_in[0];
  const float* hx  = (const float*)d_in[1];
  const float* w_f = (const float*)d_in[2];
  const float* b_f = (const float*)d_in[3];
  const float* w_n = (const float*)d_in[4];
  const float* b_n = (const float*)d_in[5];
  float* out = (float*)d_out;

  bf16* A1  = (bf16*)d_ws;                       // [2048][4096] = 16 MB
  bf16* A2L = A1  + (size_t)Bdim * Ktot;         // [2048][2048] =  8 MB
  bf16* Wf  = A2L + (size_t)Bdim * KHALF;        // [2048][4096] = 16 MB
  bf16* Wn  = Wf  + (size_t)Hdim * Ktot;         // [2048][4096] = 16 MB
  bf16* OMF = Wn  + (size_t)Hdim * Ktot;         // [2048][2048] =  8 MB
  float* P1 = (float*)(OMF + (size_t)Bdim * Hdim); // [2048][2048] f32 = 16 MB
  float* P0 = out;                               // partial kpart0 lives in d_out
  // ws total: 80 MB

  prep_kernel<<<2048, 256, 0, stream>>>(w_f, w_n, hx, x, Wf, Wn, A1);

  // GEMM1 partials: A = A1 (both K-halves), W = Wf.
  gemm_kernel<<<512, 256, 0, stream>>>(A1, Ktot, A1 + KHALF, Ktot, Wf, P0, P1);
  combine1_kernel<<<2048, 256, 0, stream>>>(P0, P1, b_f, hx, OMF, A2L);

  // GEMM2 partials: A kpart0 = A2L (fg*hx, stride 2048), kpart1 = A1 right (x).
  gemm_kernel<<<512, 256, 0, stream>>>(A2L, KHALF, A1 + Hdim, Ktot, Wn, P0, P1);
  combine2_kernel<<<2048, 256, 0, stream>>>(P0, P1, b_n, OMF, A2L, out);
}

// Round 11
// 112.949 us; speedup vs baseline: 1.3324x; 1.0964x over previous
//
#include <hip/hip_runtime.h>
#include <stdint.h>

// FSUMGUCell: hy = (1-fg)*ng + fg*hx
//   fg = ( [hx|x]@w_f^T + b_f + 1 ) * 0.5
//   ng =   [fg*hx|x]@w_n^T + b_n
// B=H=I=2048, K=H+I=4096. bf16 MFMA path.
//
// Round 11: 128x64 tiles, FULL K per block, grid 512 -> 2 blocks/CU (the
// r9-proven occupancy win) with ZERO cross-block communication (r10's
// cross-XCD ticket protocol was unsound on HW). 4 waves (2x2, 64x32 each),
// BK=64 dbuf LDS = 48 KB, counted vmcnt(6), fused epilogues (r7-verified).
// GEMM2 A-source switches [A2L | x] at the K midpoint via uniform select.

#define Hdim 2048
#define Idim 2048
#define Bdim 2048
#define Ktot 4096
#define KHALF 2048
#define NSTEP 64            // Ktot / 64
#define NSTEP2 32           // K-half boundary in BK units

typedef __bf16 bf16;
typedef __bf16 bf16x8 __attribute__((ext_vector_type(8)));
typedef float  f32x4  __attribute__((ext_vector_type(4)));

__device__ __forceinline__ void gload_lds16(const bf16* g, bf16* l) {
  __builtin_amdgcn_global_load_lds(
      (const __attribute__((address_space(1))) unsigned int*)g,
      (__attribute__((address_space(3))) unsigned int*)l,
      16, 0, 0);
}

__device__ __forceinline__ void cvt8(const float* __restrict__ src, bf16* __restrict__ dst) {
  const float4* s = (const float4*)src;
  float4 a = s[0], b = s[1];
  bf16x8 o;
  o[0]=(bf16)a.x; o[1]=(bf16)a.y; o[2]=(bf16)a.z; o[3]=(bf16)a.w;
  o[4]=(bf16)b.x; o[5]=(bf16)b.y; o[6]=(bf16)b.z; o[7]=(bf16)b.w;
  *(bf16x8*)dst = o;
}

// ---- fused prep: Wf cvt | Wn cvt | A1 = [hx|x] cvt (all f32 -> bf16 x8) ----
__global__ void prep_kernel(const float* __restrict__ w_f, const float* __restrict__ w_n,
                            const float* __restrict__ hx, const float* __restrict__ x,
                            bf16* __restrict__ Wf, bf16* __restrict__ Wn,
                            bf16* __restrict__ A1) {
  const int n8 = Hdim * Ktot / 8;
  int stride = gridDim.x * blockDim.x;
  for (int i = blockIdx.x * blockDim.x + threadIdx.x; i < 3 * n8; i += stride) {
    if (i < n8) {
      cvt8(w_f + (size_t)i * 8, Wf + (size_t)i * 8);
    } else if (i < 2 * n8) {
      int j = i - n8;
      cvt8(w_n + (size_t)j * 8, Wn + (size_t)j * 8);
    } else {
      int j = i - 2 * n8;
      int e = j * 8;
      int b = e >> 12;            // / 4096
      int k = e & (Ktot - 1);
      const float* src = (k < Hdim) ? (hx + (size_t)b * Hdim + k)
                                    : (x  + (size_t)b * Idim + (k - Hdim));
      cvt8(src, A1 + (size_t)e);
    }
  }
}

// ---- 128x64 x K=4096 GEMM, 4 waves, dbuf + counted vmcnt, fused epilogue ----
// grid 512 = 16 tm x 32 tn. C[row][col] = sum_k A[row][k] * W[col][k].
// A K-halves: (Ab0,sA0) for k<2048, (Ab1,sA1) for k>=2048 (GEMM1: both = A1;
// GEMM2: A2L then A1+Hdim). LDS [buf][A 128x64 | B 64x64] bf16 = 48 KB;
// 16B-chunk XOR swizzle: LDS[row][c] holds global chunk c ^ (row&7), staged
// via inverse-swizzled global source (global_load_lds writes linearly);
// read applies the same XOR.
template<int EPI>
__global__ __launch_bounds__(256, 2)
void gemm_kernel(const bf16* __restrict__ Ab0, int sA0,
                 const bf16* __restrict__ Ab1, int sA1,
                 const bf16* __restrict__ W,
                 const float* __restrict__ bias,
                 const float* __restrict__ hx,   // EPI0 only
                 bf16* __restrict__ OMF,         // EPI0: write (1-fg) ; EPI1: read
                 bf16* __restrict__ A2L,         // EPI0: write bf16(fg*hx) ; EPI1: read
                 float* __restrict__ OUT)        // EPI1: write hy
{
  __shared__ bf16 lds[2][12288];   // [buf][ A:0..8191 | B:8192..12287 ] = 48 KB

  int bid  = blockIdx.x;
  int sbid = (bid & 7) * 64 + (bid >> 3);   // XCD swizzle (512%8==0, bijective)
  int tm = sbid >> 5, tn = sbid & 31;       // 16 x 32 tiles of 128x64

  int tid = threadIdx.x;
  int w = tid >> 6, lane = tid & 63;
  int wrow = (w >> 1) * 64;     // 2x2 wave grid over 128x64: 64x32 per wave
  int wcol = (w & 1) * 32;
  int fr = lane & 15, fq = lane >> 4;
  int swz = fr & 7;

  // staging: A 1024 + B 512 16B chunks/step, 256 thr -> 6 loads/thread.
  // Thread t: row = jj*32 + (t>>3), dest chunk t&7, src chunk (t&7)^(row&7).
  int srow = tid >> 3;                  // 0..31
  int csrc = (tid & 7) ^ (srow & 7);

  const bf16* pA0 = Ab0 + (size_t)(tm * 128 + srow) * sA0 + csrc * 8;
  const bf16* pA1 = Ab1 + (size_t)(tm * 128 + srow) * sA1 + csrc * 8;
  const bf16* pB  = W   + (size_t)(tn * 64  + srow) * Ktot + csrc * 8;
  int lb = w * 512;                     // wave-uniform LDS base; gload adds lane*16B

#define STAGE(buf, t_) do {                                                    \
    const bf16* pa_ = ((t_) < NSTEP2) ? pA0 : pA1;                             \
    size_t sa_ = ((t_) < NSTEP2) ? (size_t)sA0 : (size_t)sA1;                  \
    size_t ko_ = ((t_) < NSTEP2) ? (size_t)(t_) * 64 : (size_t)((t_) - NSTEP2) * 64; \
    _Pragma("unroll")                                                          \
    for (int jj = 0; jj < 4; ++jj)                                             \
      gload_lds16(pa_ + (size_t)jj * 32 * sa_ + ko_, &lds[buf][jj * 2048 + lb]); \
    _Pragma("unroll")                                                          \
    for (int jj = 0; jj < 2; ++jj)                                             \
      gload_lds16(pB + (size_t)jj * 32 * Ktot + (size_t)(t_) * 64,             \
                  &lds[buf][8192 + jj * 2048 + lb]);                           \
  } while (0)

  f32x4 acc[4][2] = {};

  auto compute = [&](int buf) {
    #pragma unroll
    for (int kk = 0; kk < 2; ++kk) {
      bf16x8 af[4], bv[2];
      int ch = ((kk * 4 + fq) ^ swz) * 8;
      #pragma unroll
      for (int m = 0; m < 4; ++m)
        af[m] = *(const bf16x8*)&lds[buf][(wrow + m * 16 + fr) * 64 + ch];
      #pragma unroll
      for (int n = 0; n < 2; ++n)
        bv[n] = *(const bf16x8*)&lds[buf][8192 + (wcol + n * 16 + fr) * 64 + ch];
      __builtin_amdgcn_s_setprio(1);
      #pragma unroll
      for (int m = 0; m < 4; ++m)
        #pragma unroll
        for (int n = 0; n < 2; ++n)
          acc[m][n] = __builtin_amdgcn_mfma_f32_16x16x32_bf16(af[m], bv[n], acc[m][n], 0, 0, 0);
      __builtin_amdgcn_s_setprio(0);
    }
  };

  STAGE(0, 0);
  int cur = 0;
  for (int t = 0; t < NSTEP - 1; ++t) {
    STAGE(cur ^ 1, t + 1);                             // prefetch next K-tile
    asm volatile("s_waitcnt vmcnt(6)" ::: "memory");   // cur's 6 done; next 6 fly
    __builtin_amdgcn_s_barrier();
    compute(cur);
    __builtin_amdgcn_s_barrier();                      // reads done -> buf reusable
    cur ^= 1;
  }
  asm volatile("s_waitcnt vmcnt(0)" ::: "memory");
  __builtin_amdgcn_s_barrier();
  compute(cur);
#undef STAGE

  // ---- fused epilogue. C/D layout: col = lane&15, row = (lane>>4)*4+i [m89]
  int row0 = tm * 128 + wrow + fq * 4;
  int col0 = tn * 64 + wcol + fr;
  #pragma unroll
  for (int n = 0; n < 2; ++n) {
    int gcol = col0 + n * 16;
    float bv2 = bias[gcol];
    #pragma unroll
    for (int m = 0; m < 4; ++m) {
      #pragma unroll
      for (int i = 0; i < 4; ++i) {
        int grow = row0 + m * 16 + i;
        size_t idx = (size_t)grow * Hdim + gcol;
        float v = acc[m][n][i] + bv2;
        if (EPI == 0) {
          float fg = (v + 1.0f) * 0.5f;
          OMF[idx] = (bf16)(1.0f - fg);
          A2L[idx] = (bf16)(fg * hx[idx]);
        } else {
          OUT[idx] = (float)OMF[idx] * v + (float)A2L[idx];  // (1-fg)*ng + fg*hx
        }
      }
    }
  }
}

extern "C" void kernel_launch(void* const* d_in, const int* in_sizes, int n_in,
                              void* d_out, int out_size, void* d_ws, size_t ws_size,
                              hipStream_t stream) {
  const float* x   = (const float*)d_in[0];
  const float* hx  = (const float*)d_in[1];
  const float* w_f = (const float*)d_in[2];
  const float* b_f = (const float*)d_in[3];
  const float* w_n = (const float*)d_in[4];
  const float* b_n = (const float*)d_in[5];
  float* out = (float*)d_out;

  bf16* A1  = (bf16*)d_ws;                         // [2048][4096] = 16 MB
  bf16* A2L = A1  + (size_t)Bdim * Ktot;           // [2048][2048] =  8 MB
  bf16* Wf  = A2L + (size_t)Bdim * KHALF;          // [2048][4096] = 16 MB
  bf16* Wn  = Wf  + (size_t)Hdim * Ktot;           // [2048][4096] = 16 MB
  bf16* OMF = Wn  + (size_t)Hdim * Ktot;           // [2048][2048] =  8 MB
  // ws total: 64 MB

  prep_kernel<<<2048, 256, 0, stream>>>(w_f, w_n, hx, x, Wf, Wn, A1);

  // GEMM1: A = A1 (both K-halves); fused epilogue -> OMF + A2L.
  gemm_kernel<0><<<512, 256, 0, stream>>>(A1, Ktot, A1 + KHALF, Ktot, Wf, b_f,
                                          hx, OMF, A2L, nullptr);
  // GEMM2: A = [A2L | A1 right half (x)]; fused epilogue -> hy.
  gemm_kernel<1><<<512, 256, 0, stream>>>(A2L, KHALF, A1 + Hdim, Ktot, Wn, b_n,
                                          nullptr, OMF, A2L, out);
}